// Round 1
// baseline (986.380 us; speedup 1.0000x reference)
//
#include <hip/hip_runtime.h>
#include <hip/hip_bf16.h>
#include <cstddef>
#include <cstdint>

#define N_PIX 4096
#define C_IN  256
#define K_LOW 32

// ---------------------------------------------------------------------------
// Projection: f = f_w@x+f_b (32 ch), g = g_w@x+g_b (32 ch), h = h_w@x+h_b (256)
// x is (b, 256, 4096) channel-major; outputs written PIXEL-major:
//   f_t,g_t: (b, 4096, 32)   h_t: (b, 4096, 256)
// grid (og=10, pxtile=16, b=4), block 256 (one thread per pixel, 32 out rows).
// ---------------------------------------------------------------------------
__global__ __launch_bounds__(256) void proj_kernel(
    const float* __restrict__ x,
    const float* __restrict__ fw, const float* __restrict__ fb,
    const float* __restrict__ gw, const float* __restrict__ gb,
    const float* __restrict__ hw, const float* __restrict__ hb,
    float* __restrict__ f_t, float* __restrict__ g_t, float* __restrict__ h_t)
{
  const int og  = blockIdx.x;   // 0:f 1:g 2..9:h rows (og-2)*32
  const int pt  = blockIdx.y;
  const int b   = blockIdx.z;
  const int tid = threadIdx.x;
  const int px0 = pt * 256;

  const float* w; const float* bias; float* outp; int ostride;
  if (og == 0)      { w = fw; bias = fb; outp = f_t + ((size_t)b*N_PIX + px0)*K_LOW; ostride = K_LOW; }
  else if (og == 1) { w = gw; bias = gb; outp = g_t + ((size_t)b*N_PIX + px0)*K_LOW; ostride = K_LOW; }
  else              { w = hw + (size_t)(og-2)*32*C_IN; bias = hb + (og-2)*32;
                      outp = h_t + ((size_t)b*N_PIX + px0)*C_IN + (og-2)*32; ostride = C_IN; }

  __shared__ float xs[32][256];
  __shared__ float wl[32][33];

  float acc[32];
  #pragma unroll
  for (int o = 0; o < 32; ++o) acc[o] = 0.f;

  const float* xb = x + (size_t)b*C_IN*N_PIX;

  for (int cc = 0; cc < 8; ++cc) {
    __syncthreads();
    #pragma unroll
    for (int r = 0; r < 32; ++r)
      xs[r][tid] = xb[(size_t)(cc*32 + r)*N_PIX + px0 + tid];
    #pragma unroll
    for (int i = 0; i < 4; ++i) {
      int idx = i*256 + tid; int o = idx >> 5, r = idx & 31;
      wl[o][r] = w[(size_t)o*C_IN + cc*32 + r];
    }
    __syncthreads();
    #pragma unroll
    for (int r = 0; r < 32; ++r) {
      float xv = xs[r][tid];
      #pragma unroll
      for (int o = 0; o < 32; ++o) acc[o] += wl[o][r] * xv;
    }
  }

  float* dst = outp + (size_t)tid * ostride;
  #pragma unroll
  for (int o = 0; o < 32; o += 4) {
    float4 v = make_float4(acc[o]   + bias[o],   acc[o+1] + bias[o+1],
                           acc[o+2] + bias[o+2], acc[o+3] + bias[o+3]);
    *(float4*)(dst + o) = v;
  }
}

// ---------------------------------------------------------------------------
// Flash attention, fp32 vector. Block = 64 queries (one batch), 256 threads.
// thread (qg,cseg): qg=tid>>4 owns queries 4qg..4qg+3; cseg=tid&15 owns
// channels {4cseg+64jj+e}. Key tile = 32. Online softmax across the 16-lane
// query group (shfl_xor width 16).
// ---------------------------------------------------------------------------
#define SCORE_STEP(gv, fa, fbv) \
  s0[0]+=(gv).x*(fa);  s0[1]+=(gv).y*(fa);  s0[2]+=(gv).z*(fa);  s0[3]+=(gv).w*(fa); \
  s1[0]+=(gv).x*(fbv); s1[1]+=(gv).y*(fbv); s1[2]+=(gv).z*(fbv); s1[3]+=(gv).w*(fbv);

#define PV_STEP(jj) { \
  float4 hv = *(const float4*)&h_lds[key][4*cseg + 64*(jj)]; \
  acc[0][jj].x += pq.x*hv.x; acc[0][jj].y += pq.x*hv.y; acc[0][jj].z += pq.x*hv.z; acc[0][jj].w += pq.x*hv.w; \
  acc[1][jj].x += pq.y*hv.x; acc[1][jj].y += pq.y*hv.y; acc[1][jj].z += pq.y*hv.z; acc[1][jj].w += pq.y*hv.w; \
  acc[2][jj].x += pq.z*hv.x; acc[2][jj].y += pq.z*hv.y; acc[2][jj].z += pq.z*hv.z; acc[2][jj].w += pq.z*hv.w; \
  acc[3][jj].x += pq.w*hv.x; acc[3][jj].y += pq.w*hv.y; acc[3][jj].z += pq.w*hv.z; acc[3][jj].w += pq.w*hv.w; }

__global__ __launch_bounds__(256) void attn_kernel(
    const float* __restrict__ f_t,   // (b,4096,32)  keys
    const float* __restrict__ g_t,   // (b,4096,32)  queries
    const float* __restrict__ h_t,   // (b,4096,256) values
    const float* __restrict__ t_in,  // (b,256,4096)
    const float* __restrict__ gamma_p,
    float* __restrict__ out)         // (b,256,4096)
{
  const int b    = blockIdx.y;
  const int q0   = blockIdx.x * 64;
  const int tid  = threadIdx.x;
  const int qg   = tid >> 4;   // 0..15
  const int cseg = tid & 15;   // 0..15

  __shared__ float f_lds[32][36];   // [key][kk], 16B-aligned rows
  __shared__ float h_lds[32][260];  // [key][c]
  __shared__ float p_lds[32][68];   // [key][q]
  __shared__ float g_lds[32][64];   // [kk][q]

  // stage g for this query block (once)
  #pragma unroll
  for (int i = 0; i < 8; ++i) {
    int idx = i*256 + tid;
    int q = idx >> 5, kk = idx & 31;
    g_lds[kk][q] = g_t[((size_t)b*N_PIX + q0 + q)*K_LOW + kk];
  }

  float4 acc[4][4];
  #pragma unroll
  for (int qq = 0; qq < 4; ++qq)
    #pragma unroll
    for (int jj = 0; jj < 4; ++jj) acc[qq][jj] = make_float4(0.f, 0.f, 0.f, 0.f);
  float m[4] = {-3e38f, -3e38f, -3e38f, -3e38f};
  float l[4] = {0.f, 0.f, 0.f, 0.f};

  __syncthreads();

  for (int i0 = 0; i0 < N_PIX; i0 += 32) {
    // stage f tile: 32 keys x 32 dims (one float4 per thread)
    {
      int key = tid >> 3, k4 = tid & 7;
      float4 v = *(const float4*)(f_t + ((size_t)b*N_PIX + i0 + key)*K_LOW + 4*k4);
      *(float4*)&f_lds[key][4*k4] = v;
    }
    // stage h tile: 32 keys x 256 ch (8 float4 per thread, fully coalesced)
    #pragma unroll
    for (int i = 0; i < 8; ++i) {
      int idx = i*256 + tid;
      int key = idx >> 6, c4 = idx & 63;
      float4 v = *(const float4*)(h_t + ((size_t)b*N_PIX + i0 + key)*C_IN + 4*c4);
      *(float4*)&h_lds[key][4*c4] = v;
    }
    __syncthreads();

    // ---- scores: this thread does keys k0,k0+1 for queries 4qg..4qg+3 ----
    const int k0 = 2*cseg;
    float s0[4] = {0,0,0,0}, s1[4] = {0,0,0,0};
    #pragma unroll
    for (int k4 = 0; k4 < 8; ++k4) {
      float4 fA  = *(const float4*)&f_lds[k0  ][4*k4];
      float4 fB  = *(const float4*)&f_lds[k0+1][4*k4];
      float4 g0v = *(const float4*)&g_lds[4*k4+0][4*qg];
      float4 g1v = *(const float4*)&g_lds[4*k4+1][4*qg];
      float4 g2v = *(const float4*)&g_lds[4*k4+2][4*qg];
      float4 g3v = *(const float4*)&g_lds[4*k4+3][4*qg];
      SCORE_STEP(g0v, fA.x, fB.x)
      SCORE_STEP(g1v, fA.y, fB.y)
      SCORE_STEP(g2v, fA.z, fB.z)
      SCORE_STEP(g3v, fA.w, fB.w)
    }

    // ---- online softmax across the 16-lane query group ----
    float mt[4];
    #pragma unroll
    for (int qq = 0; qq < 4; ++qq) mt[qq] = fmaxf(s0[qq], s1[qq]);
    #pragma unroll
    for (int off = 8; off > 0; off >>= 1) {
      #pragma unroll
      for (int qq = 0; qq < 4; ++qq) mt[qq] = fmaxf(mt[qq], __shfl_xor(mt[qq], off, 16));
    }
    float p0[4], p1[4], ps[4];
    #pragma unroll
    for (int qq = 0; qq < 4; ++qq) {
      float mn = fmaxf(m[qq], mt[qq]);
      float sc = __expf(m[qq] - mn);
      m[qq] = mn;
      p0[qq] = __expf(s0[qq] - mn);
      p1[qq] = __expf(s1[qq] - mn);
      ps[qq] = p0[qq] + p1[qq];
      l[qq] *= sc;
      #pragma unroll
      for (int jj = 0; jj < 4; ++jj) {
        acc[qq][jj].x *= sc; acc[qq][jj].y *= sc; acc[qq][jj].z *= sc; acc[qq][jj].w *= sc;
      }
    }
    #pragma unroll
    for (int off = 8; off > 0; off >>= 1) {
      #pragma unroll
      for (int qq = 0; qq < 4; ++qq) ps[qq] += __shfl_xor(ps[qq], off, 16);
    }
    #pragma unroll
    for (int qq = 0; qq < 4; ++qq) l[qq] += ps[qq];

    // publish p within the wave (readers are the same wave's q-group lanes)
    #pragma unroll
    for (int qq = 0; qq < 4; ++qq) {
      p_lds[k0  ][4*qg + qq] = p0[qq];
      p_lds[k0+1][4*qg + qq] = p1[qq];
    }

    // ---- PV: acc[qq][ch] += p[qq][key] * h[key][ch] ----
    #pragma unroll
    for (int key = 0; key < 32; ++key) {
      float4 pq = *(const float4*)&p_lds[key][4*qg];
      PV_STEP(0) PV_STEP(1) PV_STEP(2) PV_STEP(3)
    }
    __syncthreads();
  }

  // epilogue: out = gamma * (acc/l) + t_in   (output is (b, c, n) like input)
  const float gamma = gamma_p[0];
  #pragma unroll
  for (int qq = 0; qq < 4; ++qq) {
    float sc = gamma / l[qq];
    int j = q0 + 4*qg + qq;
    #pragma unroll
    for (int jj = 0; jj < 4; ++jj) {
      int cb = 4*cseg + 64*jj;
      size_t base = ((size_t)b*C_IN + cb)*N_PIX + j;
      out[base            ] = acc[qq][jj].x * sc + t_in[base            ];
      out[base +   N_PIX  ] = acc[qq][jj].y * sc + t_in[base +   N_PIX  ];
      out[base + 2*N_PIX  ] = acc[qq][jj].z * sc + t_in[base + 2*N_PIX  ];
      out[base + 3*N_PIX  ] = acc[qq][jj].w * sc + t_in[base + 3*N_PIX  ];
    }
  }
}

extern "C" void kernel_launch(void* const* d_in, const int* in_sizes, int n_in,
                              void* d_out, int out_size, void* d_ws, size_t ws_size,
                              hipStream_t stream) {
  const float* t_in  = (const float*)d_in[0];
  const float* fw    = (const float*)d_in[1];
  const float* fb    = (const float*)d_in[2];
  const float* gw    = (const float*)d_in[3];
  const float* gb    = (const float*)d_in[4];
  const float* hw    = (const float*)d_in[5];
  const float* hb    = (const float*)d_in[6];
  const float* gamma = (const float*)d_in[7];
  float* out = (float*)d_out;

  float* f_t = (float*)d_ws;                       // (4,4096,32)
  float* g_t = f_t + (size_t)4*N_PIX*K_LOW;        // (4,4096,32)
  float* h_t = g_t + (size_t)4*N_PIX*K_LOW;        // (4,4096,256)

  proj_kernel<<<dim3(10, 16, 4), 256, 0, stream>>>(t_in, fw, fb, gw, gb, hw, hb,
                                                   f_t, g_t, h_t);
  attn_kernel<<<dim3(64, 4), 256, 0, stream>>>(f_t, g_t, h_t, t_in, gamma, out);
}

// Round 2
// 128.218 us; speedup vs baseline: 7.6930x; 7.6930x over previous
//
#include <hip/hip_runtime.h>
#include <hip/hip_bf16.h>
#include <cstddef>
#include <cstdint>

#define N_PIX 4096
#define C_IN  256
#define K_LOW 32

typedef unsigned int uint;
typedef unsigned short ushort;
typedef __attribute__((ext_vector_type(8))) short short8;
typedef __attribute__((ext_vector_type(16))) float f32x16;

#define DEVI __device__ __forceinline__

union FragU { uint4 u; short8 s; };

DEVI f32x16 mfma32(uint4 a, uint4 b, f32x16 c) {
  FragU A, B; A.u = a; B.u = b;
  return __builtin_amdgcn_mfma_f32_32x32x16_bf16(A.s, B.s, c, 0, 0, 0);
}

DEVI uint cvt_pk_bf16(float lo, float hi) {
  uint r;
  asm("v_cvt_pk_bf16_f32 %0, %1, %2" : "=v"(r) : "v"(lo), "v"(hi));
  return r;
}

DEVI ushort f2b(float v) {
  __hip_bfloat16 h = __float2bfloat16(v);
  return *reinterpret_cast<ushort*>(&h);
}

#define ROWFN(r, hi) ((((r) & 3)) + 8 * ((r) >> 2) + 4 * (hi))

// ---------------------------------------------------------------------------
// Weight fp32 -> bf16 conversion. 81920 elems total.
// ---------------------------------------------------------------------------
__global__ __launch_bounds__(256) void wconv_kernel(
    const float* __restrict__ fw, const float* __restrict__ gw,
    const float* __restrict__ hw,
    ushort* __restrict__ fw_b, ushort* __restrict__ gw_b, ushort* __restrict__ hw_b)
{
  int i = blockIdx.x * 256 + threadIdx.x;
  if (i < 8192)        fw_b[i]         = f2b(fw[i]);
  else if (i < 16384)  gw_b[i - 8192]  = f2b(gw[i - 8192]);
  else if (i < 81920)  hw_b[i - 16384] = f2b(hw[i - 16384]);
}

// ---------------------------------------------------------------------------
// Projection GEMM via MFMA 32x32x16 bf16.
// grid (rtile 5, ntile 16, b 4), 256 threads (4 waves).
// rtile 0: f+g (swapped operands, outputs pixel-major (n,32)).
// rtile 1..4: h rows, output tiled layout h_f[b][n>>5][c][n&31].
// X tile staged transposed+swizzled in LDS: row n (128B), word cw at
// physical word cw ^ (n&28).
// ---------------------------------------------------------------------------
__global__ __launch_bounds__(256) void proj_kernel(
    const float* __restrict__ x,
    const ushort* __restrict__ fw_b, const ushort* __restrict__ gw_b,
    const ushort* __restrict__ hw_b,
    const float* __restrict__ fb, const float* __restrict__ gb,
    const float* __restrict__ hb,
    ushort* __restrict__ f_t, ushort* __restrict__ g_t, ushort* __restrict__ h_f)
{
  const int rtile = blockIdx.x;
  const int n0    = blockIdx.y * 256;
  const int b     = blockIdx.z;
  const int tid   = threadIdx.x;
  const int w     = tid >> 6;
  const int lane  = tid & 63;
  const int hi    = lane >> 5;
  const int c31   = lane & 31;

  __shared__ ushort xt[256 * 64];   // 32 KB, row n: 64 ushort = 32 words

  f32x16 acc[2][2];
  #pragma unroll
  for (int a = 0; a < 2; ++a)
    #pragma unroll
    for (int bb = 0; bb < 2; ++bb)
      #pragma unroll
      for (int r = 0; r < 16; ++r) acc[a][bb][r] = 0.f;

  const float* xb = x + (size_t)b * C_IN * N_PIX + n0;

  for (int kc = 0; kc < 4; ++kc) {
    __syncthreads();
    // stage 64 c x 256 n, transposed to [n][c] bf16 with word swizzle
    #pragma unroll
    for (int it = 0; it < 8; ++it) {
      const float* src = xb + (size_t)(kc * 64 + it * 8) * N_PIX + tid;
      float v0 = src[0 * N_PIX], v1 = src[1 * N_PIX], v2 = src[2 * N_PIX], v3 = src[3 * N_PIX];
      float v4 = src[4 * N_PIX], v5 = src[5 * N_PIX], v6 = src[6 * N_PIX], v7 = src[7 * N_PIX];
      uint4 pkd = make_uint4(cvt_pk_bf16(v0, v1), cvt_pk_bf16(v2, v3),
                             cvt_pk_bf16(v4, v5), cvt_pk_bf16(v6, v7));
      *(uint4*)&xt[tid * 64 + 2 * ((it * 4) ^ (tid & 28))] = pkd;
    }
    __syncthreads();

    #pragma unroll
    for (int ks = 0; ks < 4; ++ks) {
      const int koff = kc * 64 + ks * 16 + hi * 8;   // element offset in K=256
      const int wrd  = ks * 8 + hi * 4;              // word offset in row
      if (rtile == 0) {
        int na = w * 64 + c31, nb = w * 64 + 32 + c31;
        uint4 aX0 = *(const uint4*)&xt[na * 64 + 2 * (wrd ^ (na & 28))];
        uint4 aX1 = *(const uint4*)&xt[nb * 64 + 2 * (wrd ^ (nb & 28))];
        uint4 bF  = *(const uint4*)(fw_b + c31 * 256 + koff);
        uint4 bG  = *(const uint4*)(gw_b + c31 * 256 + koff);
        acc[0][0] = mfma32(aX0, bF, acc[0][0]);
        acc[1][0] = mfma32(aX1, bF, acc[1][0]);
        acc[0][1] = mfma32(aX0, bG, acc[0][1]);
        acc[1][1] = mfma32(aX1, bG, acc[1][1]);
      } else {
        uint4 aW0 = *(const uint4*)(hw_b + (size_t)((rtile - 1) * 64 + c31) * 256 + koff);
        uint4 aW1 = *(const uint4*)(hw_b + (size_t)((rtile - 1) * 64 + 32 + c31) * 256 + koff);
        int na = w * 64 + c31, nb = w * 64 + 32 + c31;
        uint4 bX0 = *(const uint4*)&xt[na * 64 + 2 * (wrd ^ (na & 28))];
        uint4 bX1 = *(const uint4*)&xt[nb * 64 + 2 * (wrd ^ (nb & 28))];
        acc[0][0] = mfma32(aW0, bX0, acc[0][0]);
        acc[0][1] = mfma32(aW0, bX1, acc[0][1]);
        acc[1][0] = mfma32(aW1, bX0, acc[1][0]);
        acc[1][1] = mfma32(aW1, bX1, acc[1][1]);
      }
    }
  }

  if (rtile == 0) {
    float bfv = fb[c31], bgv = gb[c31];
    #pragma unroll
    for (int mi = 0; mi < 2; ++mi)
      #pragma unroll
      for (int r = 0; r < 16; ++r) {
        int n = n0 + w * 64 + mi * 32 + ROWFN(r, hi);
        f_t[((size_t)b * N_PIX + n) * K_LOW + c31] = f2b(acc[mi][0][r] + bfv);
        g_t[((size_t)b * N_PIX + n) * K_LOW + c31] = f2b(acc[mi][1][r] + bgv);
      }
  } else {
    #pragma unroll
    for (int mi = 0; mi < 2; ++mi)
      #pragma unroll
      for (int ni = 0; ni < 2; ++ni) {
        int nbase = n0 + w * 64 + ni * 32;
        int I = nbase >> 5;
        #pragma unroll
        for (int r = 0; r < 16; ++r) {
          int crow = (rtile - 1) * 64 + mi * 32 + ROWFN(r, hi);
          h_f[((size_t)(b * 128 + I) * C_IN + crow) * 32 + c31] =
              f2b(acc[mi][ni][r] + hb[crow]);
        }
      }
  }
}

// ---------------------------------------------------------------------------
// Flash attention, MFMA 32x32x16 bf16, fp32 accum.
// grid (64 qblocks, 4 batch), 512 threads = 8 waves.
// wave w: c-slice ws=w&3 (64 ch), key-group kg=w>>2 (2048 keys each).
// Per key-tile (32 keys): S^T = F x G^T (4 mfma), in-register softmax
// (reduction over i is lane-local + one shfl_xor(32)), P packed to bf16
// B-fragments via cvt_pk + shfl_xor(32), PV: accT += H^T x P^T (8 mfma).
// No LDS / no barriers in the key loop. End: 2-partial merge via LDS.
// ---------------------------------------------------------------------------
__global__ __launch_bounds__(512) void attn_kernel(
    const ushort* __restrict__ f_t,   // (b, n, 32) keys
    const ushort* __restrict__ g_t,   // (b, n, 32) queries
    const ushort* __restrict__ h_f,   // (b, n>>5, c, 32) values (tiled)
    const float* __restrict__ t_in,   // (b, c, n)
    const float* __restrict__ gamma_p,
    float* __restrict__ out)          // (b, c, n)
{
  const int b   = blockIdx.y;
  const int q0  = blockIdx.x * 64;
  const int tid = threadIdx.x;
  const int w    = tid >> 6;
  const int lane = tid & 63;
  const int hi   = lane >> 5;
  const int c31  = lane & 31;
  const int ws   = w & 3;
  const int kg   = w >> 2;

  __shared__ float mbuf[10240];   // 32KB acc-merge + 8KB m/l

  // hoist G fragments: B[k][j] = g[j][k]
  uint4 gB[2][2];
  #pragma unroll
  for (int kh = 0; kh < 2; ++kh)
    #pragma unroll
    for (int jn = 0; jn < 2; ++jn)
      gB[kh][jn] = *(const uint4*)(g_t +
          ((size_t)(b * N_PIX + q0 + jn * 32 + c31)) * K_LOW + kh * 16 + hi * 8);

  f32x16 acc[2][2];
  #pragma unroll
  for (int a = 0; a < 2; ++a)
    #pragma unroll
    for (int bb = 0; bb < 2; ++bb)
      #pragma unroll
      for (int r = 0; r < 16; ++r) acc[a][bb][r] = 0.f;

  float m0 = -1e30f, m1 = -1e30f, l0 = 0.f, l1 = 0.f;

  const ushort* fbase = f_t + (size_t)b * N_PIX * K_LOW;
  const ushort* hbase = h_f + (size_t)b * 128 * C_IN * 32;

  #pragma unroll 1
  for (int t = 0; t < 64; ++t) {
    const int I = kg * 64 + t;
    const int i0 = I * 32;

    // F fragments: A[i][k] = f[i][k]
    const ushort* fr = fbase + (size_t)(i0 + c31) * K_LOW + hi * 8;
    uint4 fA0 = *(const uint4*)(fr);
    uint4 fA1 = *(const uint4*)(fr + 16);

    // H fragments: A[c][i] = h[c][i] from tiled layout
    const ushort* hb0 = hbase + (size_t)I * C_IN * 32;
    uint4 hA[2][2];
    #pragma unroll
    for (int kh = 0; kh < 2; ++kh)
      #pragma unroll
      for (int mi = 0; mi < 2; ++mi)
        hA[kh][mi] = *(const uint4*)(hb0 +
            (size_t)(ws * 64 + mi * 32 + c31) * 32 + kh * 16 + hi * 8);

    // QK^T (swapped): S^T[i][j], K=32 via 2 mfma
    f32x16 s0, s1;
    #pragma unroll
    for (int r = 0; r < 16; ++r) { s0[r] = 0.f; s1[r] = 0.f; }
    s0 = mfma32(fA0, gB[0][0], s0);
    s0 = mfma32(fA1, gB[1][0], s0);
    s1 = mfma32(fA0, gB[0][1], s1);
    s1 = mfma32(fA1, gB[1][1], s1);

    // softmax over i (16 own values + partner half via shfl_xor 32)
    float mx0 = s0[0], mx1 = s1[0];
    #pragma unroll
    for (int r = 1; r < 16; ++r) { mx0 = fmaxf(mx0, s0[r]); mx1 = fmaxf(mx1, s1[r]); }
    mx0 = fmaxf(mx0, __shfl_xor(mx0, 32));
    mx1 = fmaxf(mx1, __shfl_xor(mx1, 32));

    bool need = (mx0 > m0 + 8.f) || (mx1 > m1 + 8.f);
    if (__ballot(need)) {
      float mn0 = fmaxf(m0, mx0), mn1 = fmaxf(m1, mx1);
      float sc0 = __expf(m0 - mn0), sc1 = __expf(m1 - mn1);
      #pragma unroll
      for (int mi = 0; mi < 2; ++mi)
        #pragma unroll
        for (int r = 0; r < 16; ++r) {
          acc[mi][0][r] *= sc0;
          acc[mi][1][r] *= sc1;
        }
      l0 *= sc0; l1 *= sc1; m0 = mn0; m1 = mn1;
    }

    f32x16 p0, p1;
    float sum0 = 0.f, sum1 = 0.f;
    #pragma unroll
    for (int r = 0; r < 16; ++r) {
      p0[r] = __expf(s0[r] - m0);
      p1[r] = __expf(s1[r] - m1);
      sum0 += p0[r]; sum1 += p1[r];
    }
    sum0 += __shfl_xor(sum0, 32);
    sum1 += __shfl_xor(sum1, 32);
    l0 += sum0; l1 += sum1;

    // pack P -> bf16 B-fragments (in-register, T12 pattern)
    uint4 pB[2][2];
    #pragma unroll
    for (int jn = 0; jn < 2; ++jn) {
      const f32x16& p = jn ? p1 : p0;
      uint k0 = cvt_pk_bf16(p[0],  p[1]),  k1 = cvt_pk_bf16(p[2],  p[3]);
      uint k2 = cvt_pk_bf16(p[4],  p[5]),  k3 = cvt_pk_bf16(p[6],  p[7]);
      uint k4 = cvt_pk_bf16(p[8],  p[9]),  k5 = cvt_pk_bf16(p[10], p[11]);
      uint k6 = cvt_pk_bf16(p[12], p[13]), k7 = cvt_pk_bf16(p[14], p[15]);
      uint o0 = __shfl_xor(k0, 32), o1 = __shfl_xor(k1, 32);
      uint o2 = __shfl_xor(k2, 32), o3 = __shfl_xor(k3, 32);
      uint o4 = __shfl_xor(k4, 32), o5 = __shfl_xor(k5, 32);
      uint o6 = __shfl_xor(k6, 32), o7 = __shfl_xor(k7, 32);
      pB[0][jn] = hi ? make_uint4(o2, o3, k2, k3) : make_uint4(k0, k1, o0, o1);
      pB[1][jn] = hi ? make_uint4(o6, o7, k6, k7) : make_uint4(k4, k5, o4, o5);
    }

    // PV: accT[c][j] += H^T x P^T
    #pragma unroll
    for (int kh = 0; kh < 2; ++kh)
      #pragma unroll
      for (int mi = 0; mi < 2; ++mi)
        #pragma unroll
        for (int jn = 0; jn < 2; ++jn)
          acc[mi][jn] = mfma32(hA[kh][mi], pB[kh][jn], acc[mi][jn]);
  }

  // ---- merge the two key-group partials (waves w and w^4) ----
  __syncthreads();
  {
    int mlb = 8192 + (w * 64 + lane) * 4;
    mbuf[mlb + 0] = m0; mbuf[mlb + 1] = l0;
    mbuf[mlb + 2] = m1; mbuf[mlb + 3] = l1;
  }
  __syncthreads();
  int plb = 8192 + ((w ^ 4) * 64 + lane) * 4;
  float pm0 = mbuf[plb + 0], pl0 = mbuf[plb + 1];
  float pm1 = mbuf[plb + 2], pl1 = mbuf[plb + 3];
  float mf0 = fmaxf(m0, pm0), mf1 = fmaxf(m1, pm1);
  float a0 = __expf(m0 - mf0), a1 = __expf(m1 - mf1);
  float pa0 = __expf(pm0 - mf0), pa1 = __expf(pm1 - mf1);
  float lf0 = l0 * a0 + pl0 * pa0;
  float lf1 = l1 * a1 + pl1 * pa1;

  #pragma unroll
  for (int jn = 0; jn < 2; ++jn) {
    float sc = jn ? a1 : a0;
    if (kg == 1) {
      #pragma unroll
      for (int mi = 0; mi < 2; ++mi)
        #pragma unroll
        for (int r = 0; r < 16; ++r)
          mbuf[((ws * 64 + lane) * 2 + mi) * 16 + r] = acc[mi][jn][r] * sc;
    }
    __syncthreads();
    if (kg == 0) {
      #pragma unroll
      for (int mi = 0; mi < 2; ++mi)
        #pragma unroll
        for (int r = 0; r < 16; ++r)
          acc[mi][jn][r] = acc[mi][jn][r] * sc +
                           mbuf[((ws * 64 + lane) * 2 + mi) * 16 + r];
    }
    __syncthreads();
  }

  if (kg == 0) {
    const float ga = gamma_p[0];
    float inv0 = ga / lf0, inv1 = ga / lf1;
    #pragma unroll
    for (int mi = 0; mi < 2; ++mi)
      #pragma unroll
      for (int jn = 0; jn < 2; ++jn) {
        float inv = jn ? inv1 : inv0;
        #pragma unroll
        for (int r = 0; r < 16; ++r) {
          int c = ws * 64 + mi * 32 + ROWFN(r, hi);
          int j = q0 + jn * 32 + c31;
          size_t off = ((size_t)b * C_IN + c) * N_PIX + j;
          out[off] = acc[mi][jn][r] * inv + t_in[off];
        }
      }
  }
}

extern "C" void kernel_launch(void* const* d_in, const int* in_sizes, int n_in,
                              void* d_out, int out_size, void* d_ws, size_t ws_size,
                              hipStream_t stream) {
  const float* t_in  = (const float*)d_in[0];
  const float* fw    = (const float*)d_in[1];
  const float* fb    = (const float*)d_in[2];
  const float* gw    = (const float*)d_in[3];
  const float* gb    = (const float*)d_in[4];
  const float* hw    = (const float*)d_in[5];
  const float* hb    = (const float*)d_in[6];
  const float* gamma = (const float*)d_in[7];
  float* out = (float*)d_out;

  char* ws = (char*)d_ws;
  ushort* fw_b = (ushort*)(ws);                    // 8192 elems
  ushort* gw_b = (ushort*)(ws + 16384);            // 8192
  ushort* hw_b = (ushort*)(ws + 32768);            // 65536
  ushort* f_t  = (ushort*)(ws + 163840);           // 4*4096*32
  ushort* g_t  = (ushort*)(ws + 1212416);          // 4*4096*32
  ushort* h_f  = (ushort*)(ws + 2260992);          // 4*128*256*32

  wconv_kernel<<<dim3(320), 256, 0, stream>>>(fw, gw, hw, fw_b, gw_b, hw_b);
  proj_kernel<<<dim3(5, 16, 4), 256, 0, stream>>>(
      t_in, fw_b, gw_b, hw_b, fb, gb, hb, f_t, g_t, h_f);
  attn_kernel<<<dim3(64, 4), 512, 0, stream>>>(
      f_t, g_t, h_f, t_in, gamma, out);
}

// Round 3
// 95.616 us; speedup vs baseline: 10.3160x; 1.3410x over previous
//
#include <hip/hip_runtime.h>
#include <hip/hip_bf16.h>
#include <cstddef>
#include <cstdint>

#define N_PIX 4096
#define C_IN  256
#define K_LOW 32

typedef unsigned int uint;
typedef unsigned short ushort;
typedef __attribute__((ext_vector_type(8))) short short8;
typedef __attribute__((ext_vector_type(16))) float f32x16;

#define DEVI __device__ __forceinline__

union FragU { uint4 u; short8 s; };

DEVI f32x16 mfma32(uint4 a, uint4 b, f32x16 c) {
  FragU A, B; A.u = a; B.u = b;
  return __builtin_amdgcn_mfma_f32_32x32x16_bf16(A.s, B.s, c, 0, 0, 0);
}

DEVI uint cvt_pk_bf16(float lo, float hi) {
  uint r;
  asm("v_cvt_pk_bf16_f32 %0, %1, %2" : "=v"(r) : "v"(lo), "v"(hi));
  return r;
}

DEVI ushort f2b(float v) {
  __hip_bfloat16 h = __float2bfloat16(v);
  return *reinterpret_cast<ushort*>(&h);
}

DEVI float fmax3(float a, float b, float c) {
  float d;
  asm("v_max3_f32 %0, %1, %2, %3" : "=v"(d) : "v"(a), "v"(b), "v"(c));
  return d;
}

DEVI void pswap(uint& a, uint& b) {
  asm("v_permlane32_swap_b32 %0, %1" : "+v"(a), "+v"(b));
}
DEVI void pswapf(float& a, float& b) {
  asm("v_permlane32_swap_b32 %0, %1" : "+v"(a), "+v"(b));
}

#define ROWFN(r, hi) ((((r) & 3)) + 8 * ((r) >> 2) + 4 * (hi))

// ---------------------------------------------------------------------------
// Weight fp32 -> bf16 conversion.
// ---------------------------------------------------------------------------
__global__ __launch_bounds__(256) void wconv_kernel(
    const float* __restrict__ fw, const float* __restrict__ gw,
    const float* __restrict__ hw,
    ushort* __restrict__ fw_b, ushort* __restrict__ gw_b, ushort* __restrict__ hw_b)
{
  int i = blockIdx.x * 256 + threadIdx.x;
  if (i < 8192)        fw_b[i]         = f2b(fw[i]);
  else if (i < 16384)  gw_b[i - 8192]  = f2b(gw[i - 8192]);
  else if (i < 81920)  hw_b[i - 16384] = f2b(hw[i - 16384]);
}

// ---------------------------------------------------------------------------
// Transpose x (b,c,n) fp32 -> xT (b,n,c) bf16. Tile 64c x 256n per block.
// grid (16 ntiles, 4 cgroups, 4 b), 256 threads.
// LDS word layout: row n has 32 words; word w stored at w ^ (n&28).
// ---------------------------------------------------------------------------
__global__ __launch_bounds__(256) void xpose_kernel(
    const float* __restrict__ x, ushort* __restrict__ xT)
{
  const int n0 = blockIdx.x * 256;
  const int c0 = blockIdx.y * 64;
  const int b  = blockIdx.z;
  const int tid = threadIdx.x;

  __shared__ uint xt[256 * 32];

  const float* src = x + ((size_t)b * C_IN + c0) * N_PIX + n0 + tid;
  #pragma unroll
  for (int r8 = 0; r8 < 8; ++r8) {
    float v0 = src[(size_t)(r8 * 8 + 0) * N_PIX], v1 = src[(size_t)(r8 * 8 + 1) * N_PIX];
    float v2 = src[(size_t)(r8 * 8 + 2) * N_PIX], v3 = src[(size_t)(r8 * 8 + 3) * N_PIX];
    float v4 = src[(size_t)(r8 * 8 + 4) * N_PIX], v5 = src[(size_t)(r8 * 8 + 5) * N_PIX];
    float v6 = src[(size_t)(r8 * 8 + 6) * N_PIX], v7 = src[(size_t)(r8 * 8 + 7) * N_PIX];
    uint4 pkd = make_uint4(cvt_pk_bf16(v0, v1), cvt_pk_bf16(v2, v3),
                           cvt_pk_bf16(v4, v5), cvt_pk_bf16(v6, v7));
    *(uint4*)&xt[tid * 32 + ((r8 * 4) ^ (tid & 28))] = pkd;
  }
  __syncthreads();
  #pragma unroll
  for (int it = 0; it < 8; ++it) {
    int idx = it * 256 + tid;
    int n = idx >> 3, q4 = idx & 7;
    uint4 v = *(uint4*)&xt[n * 32 + ((q4 * 4) ^ (n & 28))];
    *(uint4*)(xT + ((size_t)b * N_PIX + n0 + n) * C_IN + c0 + q4 * 8) = v;
  }
}

// ---------------------------------------------------------------------------
// Projection GEMM, pure global-fragment MFMA (no LDS).
// grid (10 rtiles, 16 ntiles, 4 b), 256 threads = 4 waves, each wave 64 n.
// rt 0: f, rt 1: g  (A = X rows n, B = W -> out (n,32) pixel-major)
// rt 2..9: h rows   (A = W rows c, B = X -> out tiled h_f[b][n>>5][c][n&31])
// ---------------------------------------------------------------------------
__global__ __launch_bounds__(256) void proj_kernel(
    const ushort* __restrict__ xT,
    const ushort* __restrict__ fw_b, const ushort* __restrict__ gw_b,
    const ushort* __restrict__ hw_b,
    const float* __restrict__ fb, const float* __restrict__ gb,
    const float* __restrict__ hb,
    ushort* __restrict__ f_t, ushort* __restrict__ g_t, ushort* __restrict__ h_f)
{
  const int rt  = blockIdx.x;
  const int b   = blockIdx.z;
  const int tid = threadIdx.x;
  const int w    = tid >> 6;
  const int lane = tid & 63;
  const int hi   = lane >> 5;
  const int c31  = lane & 31;
  const int n0   = blockIdx.y * 256 + w * 64;

  const ushort* xTb = xT + (size_t)b * N_PIX * C_IN;
  const ushort* xr0 = xTb + (size_t)(n0 + c31) * C_IN;
  const ushort* xr1 = xTb + (size_t)(n0 + 32 + c31) * C_IN;

  f32x16 acc0, acc1;
  #pragma unroll
  for (int r = 0; r < 16; ++r) { acc0[r] = 0.f; acc1[r] = 0.f; }

  if (rt < 2) {
    const ushort* wb = (rt == 0) ? fw_b : gw_b;
    const ushort* wr = wb + (size_t)c31 * C_IN;
    #pragma unroll
    for (int ks = 0; ks < 16; ++ks) {
      const int koff = ks * 16 + hi * 8;
      uint4 x0 = *(const uint4*)(xr0 + koff);
      uint4 x1 = *(const uint4*)(xr1 + koff);
      uint4 wv = *(const uint4*)(wr + koff);
      acc0 = mfma32(x0, wv, acc0);
      acc1 = mfma32(x1, wv, acc1);
    }
    const float* bias = (rt == 0) ? fb : gb;
    ushort* dst = (rt == 0) ? f_t : g_t;
    float bv = bias[c31];
    #pragma unroll
    for (int r = 0; r < 16; ++r) {
      int row = ROWFN(r, hi);
      int na = n0 + row, nb2 = n0 + 32 + row;
      dst[((size_t)b * N_PIX + na) * K_LOW + c31]  = f2b(acc0[r] + bv);
      dst[((size_t)b * N_PIX + nb2) * K_LOW + c31] = f2b(acc1[r] + bv);
    }
  } else {
    const ushort* wr = hw_b + (size_t)((rt - 2) * 32 + c31) * C_IN;
    #pragma unroll
    for (int ks = 0; ks < 16; ++ks) {
      const int koff = ks * 16 + hi * 8;
      uint4 x0 = *(const uint4*)(xr0 + koff);
      uint4 x1 = *(const uint4*)(xr1 + koff);
      uint4 wv = *(const uint4*)(wr + koff);
      acc0 = mfma32(wv, x0, acc0);
      acc1 = mfma32(wv, x1, acc1);
    }
    #pragma unroll
    for (int ni = 0; ni < 2; ++ni) {
      int I = (n0 + ni * 32) >> 5;
      const f32x16& a = ni ? acc1 : acc0;
      #pragma unroll
      for (int r = 0; r < 16; ++r) {
        int c = (rt - 2) * 32 + ROWFN(r, hi);
        h_f[((size_t)(b * 128 + I) * C_IN + c) * 32 + c31] = f2b(a[r] + hb[c]);
      }
    }
  }
}

// ---------------------------------------------------------------------------
// Flash attention, MFMA 32x32x16 bf16, fp32 accum.
// grid 256 blocks (bid bits: [7:3]+[0]->qblock, [2:1]->batch for XCD-L2
// affinity), 512 threads = 8 waves: ws=w&1 (128-ch slice), kg=w>>1 (4-way
// key split, 1024 keys each). Per key-tile: QK 4 mfma, in-register softmax
// (v_max3 + permlane32_swap, no DS ops), P pack via cvt_pk+permlane32_swap,
// PV 16 mfma. No LDS/barriers in loop; 4-way LDS merge at end.
// ---------------------------------------------------------------------------
__global__ __launch_bounds__(512) void attn_kernel(
    const ushort* __restrict__ f_t,   // (b, n, 32) keys
    const ushort* __restrict__ g_t,   // (b, n, 32) queries
    const ushort* __restrict__ h_f,   // (b, n>>5, c, 32) values (tiled)
    const float* __restrict__ t_in,   // (b, c, n)
    const float* __restrict__ gamma_p,
    float* __restrict__ out)          // (b, c, n)
{
  const int bid = blockIdx.x;
  const int b   = (bid >> 1) & 3;
  const int q0  = ((bid >> 3) * 2 + (bid & 1)) * 64;
  const int tid = threadIdx.x;
  const int w    = tid >> 6;
  const int lane = tid & 63;
  const int hi   = lane >> 5;
  const int c31  = lane & 31;
  const int ws   = w & 1;
  const int kg   = w >> 1;

  __shared__ float smem[8704];   // [0,8192): merge buf, [8192,8704): m/l

  uint4 gB[2][2];
  #pragma unroll
  for (int kh = 0; kh < 2; ++kh)
    #pragma unroll
    for (int jn = 0; jn < 2; ++jn)
      gB[kh][jn] = *(const uint4*)(g_t +
          ((size_t)b * N_PIX + q0 + jn * 32 + c31) * K_LOW + kh * 16 + hi * 8);

  f32x16 acc[4][2];   // [mi][jn]
  #pragma unroll
  for (int mi = 0; mi < 4; ++mi)
    #pragma unroll
    for (int jn = 0; jn < 2; ++jn)
      #pragma unroll
      for (int r = 0; r < 16; ++r) acc[mi][jn][r] = 0.f;

  float m0 = -1e30f, m1 = -1e30f, l0 = 0.f, l1 = 0.f;

  const ushort* fr = f_t + (size_t)b * N_PIX * K_LOW + ((size_t)kg * 1024 + c31) * K_LOW + hi * 8;
  const ushort* hp = h_f + (size_t)b * 128 * C_IN * 32 + (size_t)kg * 32 * C_IN * 32
                     + (size_t)(ws * 128 + c31) * 32;

  #pragma unroll 1
  for (int t = 0; t < 32; ++t) {
    // value fragments first (longest time to cover latency)
    uint4 hA[2][4];
    #pragma unroll
    for (int kh = 0; kh < 2; ++kh)
      #pragma unroll
      for (int mi = 0; mi < 4; ++mi)
        hA[kh][mi] = *(const uint4*)(hp + mi * 1024 + kh * 16 + hi * 8);

    uint4 fA0 = *(const uint4*)(fr);
    uint4 fA1 = *(const uint4*)(fr + 16);

    // QK^T (swapped): S^T[i][j]
    f32x16 s0, s1;
    #pragma unroll
    for (int r = 0; r < 16; ++r) { s0[r] = 0.f; s1[r] = 0.f; }
    s0 = mfma32(fA0, gB[0][0], s0);
    s0 = mfma32(fA1, gB[1][0], s0);
    s1 = mfma32(fA0, gB[0][1], s1);
    s1 = mfma32(fA1, gB[1][1], s1);

    // row-max over i: max3 chain + cross-half permlane swap
    float mx0 = fmax3(s0[0], s0[1], s0[2]);
    mx0 = fmax3(mx0, s0[3], s0[4]);   mx0 = fmax3(mx0, s0[5], s0[6]);
    mx0 = fmax3(mx0, s0[7], s0[8]);   mx0 = fmax3(mx0, s0[9], s0[10]);
    mx0 = fmax3(mx0, s0[11], s0[12]); mx0 = fmax3(mx0, s0[13], s0[14]);
    mx0 = fmaxf(mx0, s0[15]);
    float mx1 = fmax3(s1[0], s1[1], s1[2]);
    mx1 = fmax3(mx1, s1[3], s1[4]);   mx1 = fmax3(mx1, s1[5], s1[6]);
    mx1 = fmax3(mx1, s1[7], s1[8]);   mx1 = fmax3(mx1, s1[9], s1[10]);
    mx1 = fmax3(mx1, s1[11], s1[12]); mx1 = fmax3(mx1, s1[13], s1[14]);
    mx1 = fmaxf(mx1, s1[15]);
    { float a = mx0, bb = mx0; pswapf(a, bb); mx0 = fmaxf(a, bb); }
    { float a = mx1, bb = mx1; pswapf(a, bb); mx1 = fmaxf(a, bb); }

    // defer-max rescale
    bool need = (mx0 > m0 + 8.f) || (mx1 > m1 + 8.f);
    if (__ballot(need)) {
      float mn0 = fmaxf(m0, mx0), mn1 = fmaxf(m1, mx1);
      float sc0 = __expf(m0 - mn0), sc1 = __expf(m1 - mn1);
      #pragma unroll
      for (int mi = 0; mi < 4; ++mi)
        #pragma unroll
        for (int r = 0; r < 16; ++r) {
          acc[mi][0][r] *= sc0;
          acc[mi][1][r] *= sc1;
        }
      l0 *= sc0; l1 *= sc1; m0 = mn0; m1 = mn1;
    }

    // p = exp(s - m) in place, tree sums
    #pragma unroll
    for (int r = 0; r < 16; ++r) {
      s0[r] = __expf(s0[r] - m0);
      s1[r] = __expf(s1[r] - m1);
    }
    float u0[4], u1[4];
    #pragma unroll
    for (int q = 0; q < 4; ++q) {
      u0[q] = (s0[4*q] + s0[4*q+1]) + (s0[4*q+2] + s0[4*q+3]);
      u1[q] = (s1[4*q] + s1[4*q+1]) + (s1[4*q+2] + s1[4*q+3]);
    }
    float sum0 = (u0[0] + u0[1]) + (u0[2] + u0[3]);
    float sum1 = (u1[0] + u1[1]) + (u1[2] + u1[3]);
    { float a = sum0, bb = sum0; pswapf(a, bb); sum0 = a + bb; }
    { float a = sum1, bb = sum1; pswapf(a, bb); sum1 = a + bb; }
    l0 += sum0; l1 += sum1;

    // pack P -> bf16 B-fragments via cvt_pk + permlane32_swap
    uint4 pB[2][2];
    #pragma unroll
    for (int jn = 0; jn < 2; ++jn) {
      const f32x16& p = jn ? s1 : s0;
      uint k0 = cvt_pk_bf16(p[0],  p[1]),  k1 = cvt_pk_bf16(p[2],  p[3]);
      uint k2 = cvt_pk_bf16(p[4],  p[5]),  k3 = cvt_pk_bf16(p[6],  p[7]);
      uint k4 = cvt_pk_bf16(p[8],  p[9]),  k5 = cvt_pk_bf16(p[10], p[11]);
      uint k6 = cvt_pk_bf16(p[12], p[13]), k7 = cvt_pk_bf16(p[14], p[15]);
      pswap(k0, k2); pswap(k1, k3);
      pswap(k4, k6); pswap(k5, k7);
      pB[0][jn] = make_uint4(k0, k1, k2, k3);
      pB[1][jn] = make_uint4(k4, k5, k6, k7);
    }

    // PV: accT[c][j] += H^T x P^T
    #pragma unroll
    for (int kh = 0; kh < 2; ++kh)
      #pragma unroll
      for (int mi = 0; mi < 4; ++mi)
        #pragma unroll
        for (int jn = 0; jn < 2; ++jn)
          acc[mi][jn] = mfma32(hA[kh][mi], pB[kh][jn], acc[mi][jn]);

    fr += 32 * K_LOW;
    hp += C_IN * 32;
  }

  // ---- 4-way merge across kg ----
  __syncthreads();
  if (ws == 0 && lane < 32) {
    smem[8192 + (kg * 2 + 0) * 32 + c31] = m0;
    smem[8448 + (kg * 2 + 0) * 32 + c31] = l0;
    smem[8192 + (kg * 2 + 1) * 32 + c31] = m1;
    smem[8448 + (kg * 2 + 1) * 32 + c31] = l1;
  }
  __syncthreads();

  float mk0[4], lk0[4], mk1[4], lk1[4];
  #pragma unroll
  for (int k = 0; k < 4; ++k) {
    mk0[k] = smem[8192 + (k * 2 + 0) * 32 + c31];
    lk0[k] = smem[8448 + (k * 2 + 0) * 32 + c31];
    mk1[k] = smem[8192 + (k * 2 + 1) * 32 + c31];
    lk1[k] = smem[8448 + (k * 2 + 1) * 32 + c31];
  }
  float mf0 = fmax3(fmax3(mk0[0], mk0[1], mk0[2]), mk0[3], -1e30f);
  float mf1 = fmax3(fmax3(mk1[0], mk1[1], mk1[2]), mk1[3], -1e30f);
  float lf0 = 0.f, lf1 = 0.f;
  #pragma unroll
  for (int k = 0; k < 4; ++k) {
    lf0 += lk0[k] * __expf(mk0[k] - mf0);
    lf1 += lk1[k] * __expf(mk1[k] - mf1);
  }
  float a0 = __expf(m0 - mf0), a1 = __expf(m1 - mf1);
  #pragma unroll
  for (int mi = 0; mi < 4; ++mi)
    #pragma unroll
    for (int r = 0; r < 16; ++r) {
      acc[mi][0][r] *= a0;
      acc[mi][1][r] *= a1;
    }

  // chunked tree-reduce: per (jn, c-half): kg1->s0, kg3->s1; kg0+=s0, kg2+=s1;
  // kg2->s0; kg0+=s0.
  #pragma unroll
  for (int jn = 0; jn < 2; ++jn) {
    #pragma unroll
    for (int mh = 0; mh < 2; ++mh) {
      const int base0 = ((kg >> 1) * 2 + ws) * 2048;
      const int baseA = (0 * 2 + ws) * 2048;
      if (kg & 1) {
        #pragma unroll
        for (int mi2 = 0; mi2 < 2; ++mi2)
          #pragma unroll
          for (int r = 0; r < 16; ++r)
            smem[base0 + (mi2 * 32 + ROWFN(r, hi)) * 32 + c31] = acc[mh * 2 + mi2][jn][r];
      }
      __syncthreads();
      if (!(kg & 1)) {
        #pragma unroll
        for (int mi2 = 0; mi2 < 2; ++mi2)
          #pragma unroll
          for (int r = 0; r < 16; ++r)
            acc[mh * 2 + mi2][jn][r] += smem[base0 + (mi2 * 32 + ROWFN(r, hi)) * 32 + c31];
      }
      __syncthreads();
      if (kg == 2) {
        #pragma unroll
        for (int mi2 = 0; mi2 < 2; ++mi2)
          #pragma unroll
          for (int r = 0; r < 16; ++r)
            smem[baseA + (mi2 * 32 + ROWFN(r, hi)) * 32 + c31] = acc[mh * 2 + mi2][jn][r];
      }
      __syncthreads();
      if (kg == 0) {
        #pragma unroll
        for (int mi2 = 0; mi2 < 2; ++mi2)
          #pragma unroll
          for (int r = 0; r < 16; ++r)
            acc[mh * 2 + mi2][jn][r] += smem[baseA + (mi2 * 32 + ROWFN(r, hi)) * 32 + c31];
      }
      __syncthreads();
    }
  }

  if (kg == 0) {
    const float ga = gamma_p[0];
    float inv0 = ga / lf0, inv1 = ga / lf1;
    #pragma unroll
    for (int mi = 0; mi < 4; ++mi)
      #pragma unroll
      for (int jn = 0; jn < 2; ++jn) {
        float inv = jn ? inv1 : inv0;
        #pragma unroll
        for (int r = 0; r < 16; ++r) {
          int c = ws * 128 + mi * 32 + ROWFN(r, hi);
          int j = q0 + jn * 32 + c31;
          size_t off = ((size_t)b * C_IN + c) * N_PIX + j;
          out[off] = acc[mi][jn][r] * inv + t_in[off];
        }
      }
  }
}

extern "C" void kernel_launch(void* const* d_in, const int* in_sizes, int n_in,
                              void* d_out, int out_size, void* d_ws, size_t ws_size,
                              hipStream_t stream) {
  const float* t_in  = (const float*)d_in[0];
  const float* fw    = (const float*)d_in[1];
  const float* fb    = (const float*)d_in[2];
  const float* gw    = (const float*)d_in[3];
  const float* gb    = (const float*)d_in[4];
  const float* hw    = (const float*)d_in[5];
  const float* hb    = (const float*)d_in[6];
  const float* gamma = (const float*)d_in[7];
  float* out = (float*)d_out;

  char* ws = (char*)d_ws;
  ushort* fw_b = (ushort*)(ws);                    // 16 KB
  ushort* gw_b = (ushort*)(ws + 16384);            // 16 KB
  ushort* hw_b = (ushort*)(ws + 32768);            // 128 KB
  ushort* f_t  = (ushort*)(ws + 163840);           // 1 MB  (4,4096,32)
  ushort* g_t  = (ushort*)(ws + 1212416);          // 1 MB
  ushort* h_f  = (ushort*)(ws + 2260992);          // 8 MB  (4,128,256,32)
  ushort* xT   = (ushort*)(ws + 10649600);         // 8 MB  (4,4096,256)

  wconv_kernel<<<dim3(320), 256, 0, stream>>>(fw, gw, hw, fw_b, gw_b, hw_b);
  xpose_kernel<<<dim3(16, 4, 4), 256, 0, stream>>>(t_in, xT);
  proj_kernel<<<dim3(10, 16, 4), 256, 0, stream>>>(
      xT, fw_b, gw_b, hw_b, fb, gb, hb, f_t, g_t, h_f);
  attn_kernel<<<dim3(256), 512, 0, stream>>>(
      f_t, g_t, h_f, t_in, gamma, out);
}